// Round 11
// baseline (227.650 us; speedup 1.0000x reference)
//
#include <hip/hip_runtime.h>
#include <hip/hip_bf16.h>

typedef __bf16 bf16x8 __attribute__((ext_vector_type(8)));
typedef float f32x4 __attribute__((ext_vector_type(4)));
typedef unsigned int u32;
typedef unsigned short u16;
typedef u32 u32x4 __attribute__((ext_vector_type(4)));
typedef u16 u16x4 __attribute__((ext_vector_type(4)));
typedef u16 u16x8 __attribute__((ext_vector_type(8)));

// manual RNE f32->bf16 (prep kernels)
__device__ __forceinline__ u16 f2bf(float x) {
  u32 u = __float_as_uint(x);
  return (u16)((u + 0x7FFFu + ((u >> 16) & 1u)) >> 16);
}
// compiler cast (hot path)
__device__ __forceinline__ u16 cvt_bf16(float x) {
  __bf16 h = (__bf16)x;
  return __builtin_bit_cast(u16, h);
}

__device__ __forceinline__ bf16x8 ld_frag_lds(const u16* base, int byteOff) {
  u32x4 v = *(const u32x4*)((const char*)base + byteOff);
  return __builtin_bit_cast(bf16x8, v);
}
__device__ __forceinline__ bf16x8 ld_frag_glb(const u16* p) {
  u32x4 v = *(const u32x4*)p;
  return __builtin_bit_cast(bf16x8, v);
}

// ---------------------------------------------------------------------------
// prep_w:
// wfA (64 KB): Wcat = [W2a rows 64:128 (E2ji) ; rows 192:256 (E2ij)], K=128:
//   wfA[((ntg*4+ks)*64+lane)*8+q] = Wcat[ks*32+(lane>>4)*8+q][ntg*16+(lane&15)]
// wfB2 (32 KB): W2b fragments, PI-PERMUTED k-order (R10-proven):
//   element (lane(c,g), q) = W2b[64w+32t2+pi(g,q)][dt*16+c],
//   pi(g,q) = q<4 ? 4g+q : 16+4g+(q-4).
// ---------------------------------------------------------------------------
__global__ void prep_w_kernel(const float* __restrict__ W2a, const float* __restrict__ W2b,
                              u16* __restrict__ wfA, u16* __restrict__ wfB2) {
  int t = blockIdx.x * 256 + threadIdx.x;
  if (t < 4096) {  // wfA: 16 ntg * 4 ks * 64 lanes
    int lane = t & 63;
    int ks = (t >> 6) & 3;
    int ntg = t >> 8;
    int col = (ntg << 4) + (lane & 15);
    int kk = (ks << 5) + ((lane >> 4) << 3);      // 0..120
    int row = (kk < 64) ? (64 + kk) : (128 + kk); // rows 64:128 then 192:256
#pragma unroll
    for (int q = 0; q < 8; ++q)
      wfA[t * 8 + q] = f2bf(W2a[(row + q) * 256 + col]);
  } else if (t < 6144) {  // wfB2: 4 w * 2 t2 * 4 dt * 64 lanes
    int t2i = t - 4096;
    int lane = t2i & 63;
    int dt = (t2i >> 6) & 3;
    int tt = (t2i >> 8) & 1;
    int w = t2i >> 9;
    int g = lane >> 4, c = lane & 15;
    int col = (dt << 4) + c;
#pragma unroll
    for (int q = 0; q < 8; ++q) {
      int pi = (q < 4) ? (g * 4 + q) : (16 + g * 4 + (q - 4));
      int n = w * 64 + tt * 32 + pi;
      wfB2[t2i * 8 + q] = f2bf(W2b[n * 64 + col]);
    }
  }
}

// ---------------------------------------------------------------------------
// prep_T: T0p[b,n,:] = e1[b,n] @ W2a[0:64]          (f32, 2 MB)  (e1_j term)
//         T2p[b,n,:] = e1[b,n] @ W2a[128:192] + b2a (f32, 2 MB)  (e1_i term)
// Both f32 end-to-end (accuracy >= reference for these terms).
// ---------------------------------------------------------------------------
__global__ __launch_bounds__(256) void prep_T_kernel(
    const float* __restrict__ emb1, const float* __restrict__ W2a,
    const float* __restrict__ b2a, float* __restrict__ T0p, float* __restrict__ T2p) {
  __shared__ float e1row[64];
  int bn = blockIdx.x;
  int t = threadIdx.x;
  if (t < 64) e1row[t] = emb1[bn * 64 + t];
  __syncthreads();
  float a0 = 0.f;
  float a2 = b2a[t];
#pragma unroll 8
  for (int k = 0; k < 64; ++k) {
    float e = e1row[k];
    a0 += e * W2a[k * 256 + t];
    a2 += e * W2a[(128 + k) * 256 + t];
  }
  T0p[(size_t)bn * 256 + t] = a0;
  T2p[(size_t)bn * 256 + t] = a2;
}

// ---------------------------------------------------------------------------
// Fused kernel. Blocks [0,8192): out2 (dispatched first, the long pole).
// Blocks [8192,10240): out1 — pure-HBM blocks that fill out2's idle 75% of
// HBM and the dispatch tail.
//
// out2 block = (b, i, j-tile of 64)  [R10-proven skeleton]:
//   acc1 INIT = T0p[b, j, n] loads (f32; MFMA C-in accumulates them free;
//     issued first, latency hides under staging+barrier)   <- R5 fix
//   X row r = [emb2[b,j0+r,i,:] | emb2[b,i,j0+r,:]] (128 bf16, 256B rows)
//   GEMM1 (swapped, K=128): acc1 += Wcat^T @ X^T
//   GEMM2 in registers: h = relu(acc1 + T2p[b,i,n]) pi-packed -> x wfB2
//   48 KB cross-wave f32 partial exchange -> store (+b2b)
// LDS 48 KB; XOR swizzle byte^=(r&7)<<4; __launch_bounds__(256,2) (no spill).
// ---------------------------------------------------------------------------
__global__ __launch_bounds__(256, 2) void fused_kernel(
    const float* __restrict__ emb1, const float* __restrict__ emb2,
    const float* __restrict__ W1a, const float* __restrict__ b1a,
    const float* __restrict__ W1b, const float* __restrict__ b1b,
    const float* __restrict__ b2b,
    const u16* __restrict__ wfA, const u16* __restrict__ wfB2,
    const float* __restrict__ T0p, const float* __restrict__ T2p,
    float* __restrict__ out1, float* __restrict__ out2) {
  __shared__ __align__(16) u16 SH[24576];  // 48 KB; X = first 16 KB

  int blk = blockIdx.x;
  int t = threadIdx.x;

  if (blk >= 8192) {
    // ---------------- out1 path (R1-proven) ----------------
    int bi = blk - 8192;
    float* f = (float*)SH;
    float* smax = f;
    float* smin = f + 256;
    float* cat1 = f + 512;
    float* h    = f + 704;

    int d = t & 63, q = t >> 6;
    const float* base = emb2 + (size_t)bi * 256 * 64;
    float vmax = -INFINITY, vmin = INFINITY;
    for (int j = q; j < 256; j += 4) {
      float v = base[j * 64 + d];
      vmax = fmaxf(vmax, v);
      vmin = fminf(vmin, v);
    }
    smax[q * 64 + d] = vmax;
    smin[q * 64 + d] = vmin;
    __syncthreads();
    if (t < 64) {
      float mx = fmaxf(fmaxf(smax[t], smax[64 + t]), fmaxf(smax[128 + t], smax[192 + t]));
      float mn = fminf(fminf(smin[t], smin[64 + t]), fminf(smin[128 + t], smin[192 + t]));
      cat1[t] = emb1[bi * 64 + t];
      cat1[64 + t] = mx;
      cat1[128 + t] = mn;
    }
    __syncthreads();
    if (t < 128) {
      float acc = b1a[t];
      for (int k = 0; k < 192; ++k) acc += cat1[k] * W1a[k * 128 + t];
      h[t] = fmaxf(acc, 0.f);
    }
    __syncthreads();
    if (t < 64) {
      float acc = b1b[t];
      for (int k = 0; k < 128; ++k) acc += h[k] * W1b[k * 64 + t];
      out1[bi * 64 + t] = acc;
    }
    return;
  }

  // ---------------- out2 path ----------------
  int b = blk >> 10;
  int i = (blk >> 2) & 255;
  int j0 = (blk & 3) << 6;
  int lane = t & 63;
  int w = t >> 6;
  int lr = lane & 15;
  int lg = lane >> 4;

  // ---- acc1 init from T0p (issued FIRST; C-in accumulation is free) ----
  // acc1[m][nt][e]: j = j0+16m+lr, n = 64w+16nt+4lg+e
  f32x4 acc1[4][4];
  {
    const float* T0b = T0p + ((size_t)(b << 8) + j0) * 256 + (w << 6) + (lg << 2);
#pragma unroll
    for (int m = 0; m < 4; ++m)
#pragma unroll
      for (int nt = 0; nt < 4; ++nt)
        acc1[m][nt] = *(const f32x4*)(T0b + ((m << 4) + lr) * 256 + (nt << 4));
  }
  // T2p row for this (b,i): replaces b2a in the h-pack
  float4 t2v[4];
  {
    const float* T2b = T2p + ((size_t)(b << 8) + i) * 256 + (w << 6) + (lg << 2);
#pragma unroll
    for (int nt = 0; nt < 4; ++nt) t2v[nt] = *(const float4*)(T2b + (nt << 4));
  }

  // ---- stage X: 64 rows x 128 bf16 (256B rows), swizzle byte^=(r&7)<<4 ----
  {
    int r = t >> 2;
    int q = t & 3;  // 32-float chunk: q<2 -> seg1, else seg2
    const float* s1 = emb2 + ((((size_t)(b << 8) + j0 + r) << 8) + i) * 64;
    const float* s2 = emb2 + ((((size_t)(b << 8) + i) << 8) + (j0 + r)) * 64;
    const float* src = (q < 2) ? (s1 + (q << 5)) : (s2 + ((q - 2) << 5));
    int swz = (r & 7) << 4;
#pragma unroll
    for (int c = 0; c < 2; ++c) {
      const float* p = src + (c << 4);
      float4 a0 = *(const float4*)(p);
      float4 a1 = *(const float4*)(p + 4);
      float4 a2 = *(const float4*)(p + 8);
      float4 a3 = *(const float4*)(p + 12);
      u16x8 o0 = {cvt_bf16(a0.x), cvt_bf16(a0.y), cvt_bf16(a0.z), cvt_bf16(a0.w),
                  cvt_bf16(a1.x), cvt_bf16(a1.y), cvt_bf16(a1.z), cvt_bf16(a1.w)};
      u16x8 o1 = {cvt_bf16(a2.x), cvt_bf16(a2.y), cvt_bf16(a2.z), cvt_bf16(a2.w),
                  cvt_bf16(a3.x), cvt_bf16(a3.y), cvt_bf16(a3.z), cvt_bf16(a3.w)};
      int base = r * 256 + (q << 6) + (c << 5);
      *(u16x8*)((char*)SH + (base ^ swz)) = o0;
      *(u16x8*)((char*)SH + ((base + 16) ^ swz)) = o1;
    }
  }
  __syncthreads();

  // ---- GEMM1 (swapped, K=128): acc1 += Wcat^T @ X^T ----
#pragma unroll
  for (int ks = 0; ks < 4; ++ks) {
    int kByte = (ks << 6) + (lg << 4);
    bf16x8 a[4];
#pragma unroll
    for (int m = 0; m < 4; ++m) {
      int row = (m << 4) + lr;
      a[m] = ld_frag_lds(SH, (row * 256 + kByte) ^ ((lr & 7) << 4));
    }
    bf16x8 bw[4];
#pragma unroll
    for (int nt = 0; nt < 4; ++nt)
      bw[nt] = ld_frag_glb(wfA + (size_t)((((w << 2) + nt) * 4 + ks) * 64 + lane) * 8);
#pragma unroll
    for (int m = 0; m < 4; ++m)
#pragma unroll
      for (int nt = 0; nt < 4; ++nt)
        acc1[m][nt] = __builtin_amdgcn_mfma_f32_16x16x32_bf16(bw[nt], a[m], acc1[m][nt], 0, 0, 0);
  }

  __syncthreads();  // all X reads done; SH becomes the exchange region

  // ---- GEMM2 in registers (R10-proven pi-packing) ----
  // h8 q<4 : relu(acc1[m][2t2][q]   + t2v[2t2][q])
  //    q>=4: relu(acc1[m][2t2+1][q-4] + t2v[2t2+1][q-4])
  f32x4 acc2[4][4];  // [m][dt]: d = 16dt+4lg+e, j = 16m+lr
#pragma unroll
  for (int m = 0; m < 4; ++m)
#pragma unroll
    for (int dt = 0; dt < 4; ++dt) acc2[m][dt] = (f32x4){0.f, 0.f, 0.f, 0.f};

#pragma unroll
  for (int t2 = 0; t2 < 2; ++t2) {
    float4 ba = t2v[2 * t2];
    float4 bb = t2v[2 * t2 + 1];
    bf16x8 h[4];
#pragma unroll
    for (int m = 0; m < 4; ++m) {
      f32x4 pa = acc1[m][2 * t2];
      f32x4 pb = acc1[m][2 * t2 + 1];
      u16x8 hp = {cvt_bf16(fmaxf(pa[0] + ba.x, 0.f)), cvt_bf16(fmaxf(pa[1] + ba.y, 0.f)),
                  cvt_bf16(fmaxf(pa[2] + ba.z, 0.f)), cvt_bf16(fmaxf(pa[3] + ba.w, 0.f)),
                  cvt_bf16(fmaxf(pb[0] + bb.x, 0.f)), cvt_bf16(fmaxf(pb[1] + bb.y, 0.f)),
                  cvt_bf16(fmaxf(pb[2] + bb.z, 0.f)), cvt_bf16(fmaxf(pb[3] + bb.w, 0.f))};
      h[m] = __builtin_bit_cast(bf16x8, hp);
    }
#pragma unroll
    for (int dt = 0; dt < 4; ++dt) {
      bf16x8 wf = ld_frag_glb(wfB2 + (size_t)(((((w << 1) + t2) << 2) + dt) * 64 + lane) * 8);
#pragma unroll
      for (int m = 0; m < 4; ++m)
        acc2[m][dt] = __builtin_amdgcn_mfma_f32_16x16x32_bf16(wf, h[m], acc2[m][dt], 0, 0, 0);
    }
  }

  // ---- cross-wave reduction (R10-proven): 12 tiles x 4KB, lane*16B ----
  char* red = (char*)SH;
#pragma unroll
  for (int dt = 0; dt < 4; ++dt) {
    if (dt != w) {
      int s = dt - (dt > w ? 1 : 0);
#pragma unroll
      for (int m = 0; m < 4; ++m)
        *(f32x4*)(red + ((((w * 3 + s) << 2) + m) << 10) + (lane << 4)) = acc2[m][dt];
    }
  }
  __syncthreads();

  f32x4 accO[4];
#pragma unroll
  for (int m = 0; m < 4; ++m) {
    accO[m] = acc2[m][0];
#pragma unroll
    for (int dt = 1; dt < 4; ++dt)
      if (w == dt) accO[m] = acc2[m][dt];
  }
#pragma unroll
  for (int wp = 0; wp < 4; ++wp) {
    if (wp != w) {
      int s = w - (w > wp ? 1 : 0);
#pragma unroll
      for (int m = 0; m < 4; ++m) {
        f32x4 p = *(const f32x4*)(red + ((((wp * 3 + s) << 2) + m) << 10) + (lane << 4));
        accO[m] += p;
      }
    }
  }

  // ---- store: j = j0+16m+lr, d = 16w+4lg+e ----
  float4 bias2 = *(const float4*)(b2b + (w << 4) + (lg << 2));
  float* obase = out2 + (((size_t)(b << 8) + i) * 256 + j0) * 64 + (w << 4) + (lg << 2);
#pragma unroll
  for (int m = 0; m < 4; ++m) {
    float4 v = {accO[m][0] + bias2.x, accO[m][1] + bias2.y,
                accO[m][2] + bias2.z, accO[m][3] + bias2.w};
    *(float4*)(obase + (size_t)((m << 4) + lr) * 64) = v;
  }
}

extern "C" void kernel_launch(void* const* d_in, const int* in_sizes, int n_in,
                              void* d_out, int out_size, void* d_ws, size_t ws_size,
                              hipStream_t stream) {
  const float* emb1 = (const float*)d_in[0];
  const float* emb2 = (const float*)d_in[1];
  const float* W1a  = (const float*)d_in[2];
  const float* b1a  = (const float*)d_in[3];
  const float* W1b  = (const float*)d_in[4];
  const float* b1b  = (const float*)d_in[5];
  const float* W2a  = (const float*)d_in[6];
  const float* b2a  = (const float*)d_in[7];
  const float* W2b  = (const float*)d_in[8];
  const float* b2b  = (const float*)d_in[9];

  float* out = (float*)d_out;
  u16* wfA  = (u16*)d_ws;                  // 4096*8  = 32768 u16 = 64 KB
  u16* wfB2 = wfA + 32768;                 // 2048*8  = 16384 u16 = 32 KB
  float* T0p = (float*)(wfB2 + 16384);     // 2048*256 f32 = 2 MB
  float* T2p = T0p + 2048 * 256;           // 2 MB

  prep_w_kernel<<<24, 256, 0, stream>>>(W2a, W2b, wfA, wfB2);
  prep_T_kernel<<<2048, 256, 0, stream>>>(emb1, W2a, b2a, T0p, T2p);
  fused_kernel<<<10240, 256, 0, stream>>>(emb1, emb2, W1a, b1a, W1b, b1b,
                                          b2b, wfA, wfB2, T0p, T2p,
                                          out, out + 8 * 256 * 64);
}

// Round 12
// 159.537 us; speedup vs baseline: 1.4269x; 1.4269x over previous
//
#include <hip/hip_runtime.h>
#include <hip/hip_bf16.h>

typedef __bf16 bf16x8 __attribute__((ext_vector_type(8)));
typedef float f32x4 __attribute__((ext_vector_type(4)));
typedef unsigned int u32;
typedef unsigned short u16;
typedef u32 u32x4 __attribute__((ext_vector_type(4)));
typedef u16 u16x4 __attribute__((ext_vector_type(4)));
typedef u16 u16x8 __attribute__((ext_vector_type(8)));

// manual RNE f32->bf16 (prep kernels)
__device__ __forceinline__ u16 f2bf(float x) {
  u32 u = __float_as_uint(x);
  return (u16)((u + 0x7FFFu + ((u >> 16) & 1u)) >> 16);
}
// compiler cast (hot path)
__device__ __forceinline__ u16 cvt_bf16(float x) {
  __bf16 h = (__bf16)x;
  return __builtin_bit_cast(u16, h);
}
__device__ __forceinline__ float bf2f(u16 h) {
  return __uint_as_float((u32)h << 16);
}

__device__ __forceinline__ bf16x8 ld_frag_lds(const u16* base, int byteOff) {
  u32x4 v = *(const u32x4*)((const char*)base + byteOff);
  return __builtin_bit_cast(bf16x8, v);
}
__device__ __forceinline__ bf16x8 ld_frag_glb(const u16* p) {
  u32x4 v = *(const u32x4*)p;
  return __builtin_bit_cast(bf16x8, v);
}

// ---------------------------------------------------------------------------
// prep_w (R10-proven):
// wfA (128 KB): W2a K=256 N=256 as MFMA A-fragments:
//   wfA[((ntg*8+ks)*64+lane)*8+q] = W2a[ks*32+(lane>>4)*8+q][ntg*16+(lane&15)]
// wfB2 (32 KB): W2b fragments, PI-PERMUTED k-order:
//   element (lane(c,g), q) = W2b[64w+32t2+pi(g,q)][dt*16+c],
//   pi(g,q) = q<4 ? 4g+q : 16+4g+(q-4).
// ---------------------------------------------------------------------------
__global__ void prep_w_kernel(const float* __restrict__ W2a, const float* __restrict__ W2b,
                              u16* __restrict__ wfA, u16* __restrict__ wfB2) {
  int t = blockIdx.x * 256 + threadIdx.x;
  if (t < 8192) {  // wfA: 16 ntg * 8 ks * 64 lanes
    int lane = t & 63;
    int ks = (t >> 6) & 7;
    int ntg = t >> 9;
    int col = (ntg << 4) + (lane & 15);
    int kb = (ks << 5) + ((lane >> 4) << 3);
#pragma unroll
    for (int q = 0; q < 8; ++q)
      wfA[t * 8 + q] = f2bf(W2a[(kb + q) * 256 + col]);
  } else if (t < 10240) {  // wfB2: 4 w * 2 t2 * 4 dt * 64 lanes
    int t2i = t - 8192;
    int lane = t2i & 63;
    int dt = (t2i >> 6) & 3;
    int tt = (t2i >> 8) & 1;
    int w = t2i >> 9;
    int g = lane >> 4, c = lane & 15;
    int col = (dt << 4) + c;
#pragma unroll
    for (int q = 0; q < 8; ++q) {
      int pi = (q < 4) ? (g * 4 + q) : (16 + g * 4 + (q - 4));
      int n = w * 64 + tt * 32 + pi;
      wfB2[t2i * 8 + q] = f2bf(W2b[n * 64 + col]);
    }
  }
}

// ---------------------------------------------------------------------------
// out1: R1-proven. One block per (b,i). Launched before out2 (L3 warm).
// SEPARATE kernel — fusing it into out2 thrashes the cache out2's gathers
// rely on (+70MB FETCH, +100us; R4/R5/R11 all confirm).
// ---------------------------------------------------------------------------
__global__ __launch_bounds__(256) void out1_kernel(
    const float* __restrict__ emb1, const float* __restrict__ emb2,
    const float* __restrict__ W1a, const float* __restrict__ b1a,
    const float* __restrict__ W1b, const float* __restrict__ b1b,
    float* __restrict__ out1) {
  int bi = blockIdx.x;
  int t = threadIdx.x;
  __shared__ float smax[4][64];
  __shared__ float smin[4][64];
  __shared__ float cat1[192];
  __shared__ float h[128];

  int d = t & 63, q = t >> 6;
  const float* base = emb2 + (size_t)bi * 256 * 64;
  float vmax = -INFINITY, vmin = INFINITY;
  for (int j = q; j < 256; j += 4) {
    float v = base[j * 64 + d];
    vmax = fmaxf(vmax, v);
    vmin = fminf(vmin, v);
  }
  smax[q][d] = vmax;
  smin[q][d] = vmin;
  __syncthreads();
  if (t < 64) {
    float mx = fmaxf(fmaxf(smax[0][t], smax[1][t]), fmaxf(smax[2][t], smax[3][t]));
    float mn = fminf(fminf(smin[0][t], smin[1][t]), fminf(smin[2][t], smin[3][t]));
    cat1[t] = emb1[bi * 64 + t];
    cat1[64 + t] = mx;
    cat1[128 + t] = mn;
  }
  __syncthreads();
  if (t < 128) {
    float acc = b1a[t];
    for (int k = 0; k < 192; ++k) acc += cat1[k] * W1a[k * 128 + t];
    h[t] = fmaxf(acc, 0.f);
  }
  __syncthreads();
  if (t < 64) {
    float acc = b1b[t];
    for (int k = 0; k < 128; ++k) acc += h[k] * W1b[k * 64 + t];
    out1[bi * 64 + t] = acc;
  }
}

// ---------------------------------------------------------------------------
// out2: R10-proven skeleton, one block = (b, i, j-tile of 64).
// stage X -> bar -> GEMM1 (swapped, K=256) -> bar -> GEMM2 in registers
// (pi-packed) -> BF16 partial exchange (24 KB) -> bar -> reduce -> store.
// CHANGE vs R10: exchange partials in bf16 (12 tiles x 512B = 24 KB), so
// total LDS = 32 KB (X region reused) -> 5 blocks/CU (was 3 at 48 KB).
// More TLP to hide the s1-gather latency (the binding constraint: all
// counters ~30%, latency-bound).
// __launch_bounds__(256,2): proven no-spill envelope.
// ---------------------------------------------------------------------------
__global__ __launch_bounds__(256, 2) void out2_kernel(
    const float* __restrict__ emb1, const float* __restrict__ emb2,
    const float* __restrict__ b2a, const float* __restrict__ b2b,
    const u16* __restrict__ wfA, const u16* __restrict__ wfB2,
    float* __restrict__ out2) {
  __shared__ __align__(16) u16 SH[16384];  // 32 KB

  int blk = blockIdx.x;
  int b = blk >> 10;
  int i = (blk >> 2) & 255;
  int j0 = (blk & 3) << 6;
  int t = threadIdx.x;
  int lane = t & 63;
  int w = t >> 6;
  int lr = lane & 15;
  int lg = lane >> 4;

  // ---- stage X: 64 rows x 256 bf16 (512B rows), swizzle byte^=(r&7)<<4 ----
  {
    int r = t >> 2;
    int c16 = (t & 3) << 4;
    const float* s0 = emb1 + ((b << 8) + j0 + r) * 64;
    const float* s1 = emb2 + ((((size_t)(b << 8) + j0 + r) << 8) + i) * 64;
    const float* s2 = emb1 + ((b << 8) + i) * 64;
    const float* s3 = emb2 + ((((size_t)(b << 8) + i) << 8) + (j0 + r)) * 64;
    const float* srcs[4] = {s0, s1, s2, s3};
#pragma unroll
    for (int seg = 0; seg < 4; ++seg) {
      const float* src = srcs[seg];
#pragma unroll
      for (int u = 0; u < 2; ++u) {
        int d = c16 + (u << 3);
        float4 v0 = *(const float4*)(src + d);
        float4 v1 = *(const float4*)(src + d + 4);
        u16x8 o = {cvt_bf16(v0.x), cvt_bf16(v0.y), cvt_bf16(v0.z), cvt_bf16(v0.w),
                   cvt_bf16(v1.x), cvt_bf16(v1.y), cvt_bf16(v1.z), cvt_bf16(v1.w)};
        int byteOff = (r * 512 + ((seg << 6) + d) * 2) ^ ((r & 7) << 4);
        *(u16x8*)((char*)SH + byteOff) = o;
      }
    }
  }
  __syncthreads();

  // ---- GEMM1 (swapped): acc1[m][nt][e]: j = 16m+lr, n = 64w+16nt+4lg+e ----
  f32x4 acc1[4][4];
#pragma unroll
  for (int m = 0; m < 4; ++m)
#pragma unroll
    for (int nt = 0; nt < 4; ++nt) acc1[m][nt] = (f32x4){0.f, 0.f, 0.f, 0.f};

#pragma unroll
  for (int ks = 0; ks < 8; ++ks) {
    int kByte = (ks << 6) + (lg << 4);
    bf16x8 a[4];
#pragma unroll
    for (int m = 0; m < 4; ++m) {
      int row = (m << 4) + lr;
      a[m] = ld_frag_lds(SH, (row * 512 + kByte) ^ ((lr & 7) << 4));
    }
    bf16x8 bw[4];
#pragma unroll
    for (int nt = 0; nt < 4; ++nt)
      bw[nt] = ld_frag_glb(wfA + (size_t)((((w << 2) + nt) * 8 + ks) * 64 + lane) * 8);
#pragma unroll
    for (int m = 0; m < 4; ++m)
#pragma unroll
      for (int nt = 0; nt < 4; ++nt)
        acc1[m][nt] = __builtin_amdgcn_mfma_f32_16x16x32_bf16(bw[nt], a[m], acc1[m][nt], 0, 0, 0);
  }

  __syncthreads();  // all X reads done; SH becomes the exchange region

  // ---- GEMM2 in registers (pi-packing, R10-proven) ----
  f32x4 acc2[4][4];  // [m][dt]: d = 16dt+4lg+e, j = 16m+lr
#pragma unroll
  for (int m = 0; m < 4; ++m)
#pragma unroll
    for (int dt = 0; dt < 4; ++dt) acc2[m][dt] = (f32x4){0.f, 0.f, 0.f, 0.f};

#pragma unroll
  for (int t2 = 0; t2 < 2; ++t2) {
    int nbase = (w << 6) + (t2 << 5) + (lg << 2);
    float4 ba = *(const float4*)(b2a + nbase);
    float4 bb = *(const float4*)(b2a + nbase + 16);
    bf16x8 h[4];
#pragma unroll
    for (int m = 0; m < 4; ++m) {
      f32x4 pa = acc1[m][2 * t2];
      f32x4 pb = acc1[m][2 * t2 + 1];
      u16x8 hp = {cvt_bf16(fmaxf(pa[0] + ba.x, 0.f)), cvt_bf16(fmaxf(pa[1] + ba.y, 0.f)),
                  cvt_bf16(fmaxf(pa[2] + ba.z, 0.f)), cvt_bf16(fmaxf(pa[3] + ba.w, 0.f)),
                  cvt_bf16(fmaxf(pb[0] + bb.x, 0.f)), cvt_bf16(fmaxf(pb[1] + bb.y, 0.f)),
                  cvt_bf16(fmaxf(pb[2] + bb.z, 0.f)), cvt_bf16(fmaxf(pb[3] + bb.w, 0.f))};
      h[m] = __builtin_bit_cast(bf16x8, hp);
    }
#pragma unroll
    for (int dt = 0; dt < 4; ++dt) {
      bf16x8 wf = ld_frag_glb(wfB2 + (size_t)(((((w << 1) + t2) << 2) + dt) * 64 + lane) * 8);
#pragma unroll
      for (int m = 0; m < 4; ++m)
        acc2[m][dt] = __builtin_amdgcn_mfma_f32_16x16x32_bf16(wf, h[m], acc2[m][dt], 0, 0, 0);
    }
  }

  // ---- cross-wave reduction, BF16 partials: 12 tiles x 512B = 24 KB ----
  // tile (w, s, m) at ((w*12 + s*4 + m) << 9) + lane*8  (ds_write_b64,
  // 64 lanes cover 512B contiguous -> 2 lanes/bank = free).
  char* red = (char*)SH;
#pragma unroll
  for (int dt = 0; dt < 4; ++dt) {
    if (dt != w) {
      int s = dt - (dt > w ? 1 : 0);
#pragma unroll
      for (int m = 0; m < 4; ++m) {
        f32x4 p = acc2[m][dt];
        u16x4 o = {cvt_bf16(p[0]), cvt_bf16(p[1]), cvt_bf16(p[2]), cvt_bf16(p[3])};
        *(u16x4*)(red + (((w * 12 + s * 4 + m) << 9) + (lane << 3))) = o;
      }
    }
  }
  __syncthreads();

  // own tile (static-index select) + peers' bf16 partials
  f32x4 accO[4];
#pragma unroll
  for (int m = 0; m < 4; ++m) {
    accO[m] = acc2[m][0];
#pragma unroll
    for (int dt = 1; dt < 4; ++dt)
      if (w == dt) accO[m] = acc2[m][dt];
  }
#pragma unroll
  for (int wp = 0; wp < 4; ++wp) {
    if (wp != w) {
      int s = w - (w > wp ? 1 : 0);
#pragma unroll
      for (int m = 0; m < 4; ++m) {
        u16x4 o = *(const u16x4*)(red + (((wp * 12 + s * 4 + m) << 9) + (lane << 3)));
        accO[m][0] += bf2f(o[0]);
        accO[m][1] += bf2f(o[1]);
        accO[m][2] += bf2f(o[2]);
        accO[m][3] += bf2f(o[3]);
      }
    }
  }

  // ---- store: j = j0+16m+lr, d = 16w+4lg+e ----
  float4 bias2 = *(const float4*)(b2b + (w << 4) + (lg << 2));
  float* obase = out2 + (((size_t)(b << 8) + i) * 256 + j0) * 64 + (w << 4) + (lg << 2);
#pragma unroll
  for (int m = 0; m < 4; ++m) {
    float4 v = {accO[m][0] + bias2.x, accO[m][1] + bias2.y,
                accO[m][2] + bias2.z, accO[m][3] + bias2.w};
    *(float4*)(obase + (size_t)((m << 4) + lr) * 64) = v;
  }
}

extern "C" void kernel_launch(void* const* d_in, const int* in_sizes, int n_in,
                              void* d_out, int out_size, void* d_ws, size_t ws_size,
                              hipStream_t stream) {
  const float* emb1 = (const float*)d_in[0];
  const float* emb2 = (const float*)d_in[1];
  const float* W1a  = (const float*)d_in[2];
  const float* b1a  = (const float*)d_in[3];
  const float* W1b  = (const float*)d_in[4];
  const float* b1b  = (const float*)d_in[5];
  const float* W2a  = (const float*)d_in[6];
  const float* b2a  = (const float*)d_in[7];
  const float* W2b  = (const float*)d_in[8];
  const float* b2b  = (const float*)d_in[9];

  float* out = (float*)d_out;
  u16* wfA  = (u16*)d_ws;            // 16*8*64*8 = 65536 u16 = 128 KB
  u16* wfB2 = wfA + 65536;           //  4*2*4*64*8 = 16384 u16 = 32 KB

  prep_w_kernel<<<40, 256, 0, stream>>>(W2a, W2b, wfA, wfB2);
  // out1 first: sequential emb2 read warms L3 for out2's gathers (R10 order)
  out1_kernel<<<2048, 256, 0, stream>>>(emb1, emb2, W1a, b1a, W1b, b1b, out);
  out2_kernel<<<8192, 256, 0, stream>>>(emb1, emb2, b2a, b2b, wfA, wfB2,
                                        out + 8 * 256 * 64);
}